// Round 8
// baseline (217.075 us; speedup 1.0000x reference)
//
#include <hip/hip_runtime.h>
#include <hip/hip_bf16.h>
#include <math.h>

typedef unsigned short u16;
typedef unsigned char u8;
typedef unsigned int u32;
typedef __attribute__((ext_vector_type(4))) float f32x4;
typedef __attribute__((ext_vector_type(8))) int i32x8;

// -------------------------------------------------- fp32 -> fp8 e4m3 (x16 pre-scale)
// l2-normed inputs: |x| <~ 0.3 -> x*16 in [~0.01, 4.8]: full mantissa, no saturation.
// Dequant folded into the gemm epilogue (divide by 256*temp).
__global__ void cvt_fused(const float* __restrict__ F, const float* __restrict__ T,
                          u32* __restrict__ Fb, u32* __restrict__ Tb,
                          float* __restrict__ out) {
    const int idx = blockIdx.x * blockDim.x + threadIdx.x;
    if (idx == 0) out[0] = 0.f;
    const float* s;
    u32* d;
    int i;
    if (idx < 65536) { s = F; d = Fb; i = idx; }
    else             { s = T; d = Tb; i = idx - 65536; }
    const float4 v0 = *(const float4*)(s + (size_t)i * 8);
    const float4 v1 = *(const float4*)(s + (size_t)i * 8 + 4);
    int lo = __builtin_amdgcn_cvt_pk_fp8_f32(v0.x * 16.f, v0.y * 16.f, 0, false);
    lo     = __builtin_amdgcn_cvt_pk_fp8_f32(v0.z * 16.f, v0.w * 16.f, lo, true);
    int hi = __builtin_amdgcn_cvt_pk_fp8_f32(v1.x * 16.f, v1.y * 16.f, 0, false);
    hi     = __builtin_amdgcn_cvt_pk_fp8_f32(v1.z * 16.f, v1.w * 16.f, hi, true);
    uint2 o; o.x = (u32)lo; o.y = (u32)hi;
    ((uint2*)d)[i] = o;
}

// ---------------------------------------------------------------- GEMM + max
#define GLB_AS __attribute__((address_space(1)))
#define LDS_AS __attribute__((address_space(3)))

__device__ __forceinline__ void gload_lds16(const void* g, void* l) {
    __builtin_amdgcn_global_load_lds((const GLB_AS void*)g, (LDS_AS void*)l, 16, 0, 0);
}

// regs-only operand build: two int4 -> i32x8
__device__ __forceinline__ i32x8 mk8(int4 a, int4 b) {
    i32x8 r;
    r[0] = a.x; r[1] = a.y; r[2] = a.z; r[3] = a.w;
    r[4] = b.x; r[5] = b.y; r[6] = b.z; r[7] = b.w;
    return r;
}

// A: F fp8 [1024 x 512], B: T fp8 [32768 x 512] (row-major, K contiguous, bytes).
// sim[i*1024+j] = max_{q<32} dot(A[i],B[j*32+q]) / (256*temp)
// Tile: BM=64, BN=128, BK=128 (24 KB LDS) at __launch_bounds__(256,4):
// 4 blocks/CU -> 2x the co-resident blocks of R7 to overlap the K-loop's
// barrier drains (R7 was latency-bound: MfmaUtil 14%, occupancy 17%).
// Registers/wave: acc 32 + bf 32 + af 8 + addr ~25 < 128 cap (no spill).
// NOTE: (256,3)+big-tile spilled accumulators (R6: 500 MB scratch). This
// config keeps per-wave demand under the 4-wave cap instead.
// LDS: row-groups of 8 rows; 16B slot s of row r holds global chunk s^(r&7)
// (full XOR swizzle, conflict-free - verified R4).
__global__ __launch_bounds__(256, 4)
void gemm_max(const u8* __restrict__ A, const u8* __restrict__ B,
              const float* __restrict__ temp_ptr, float* __restrict__ sim) {
    __shared__ __align__(16) u8 lA[64 * 128];    //  8 KB
    __shared__ __align__(16) u8 lB[128 * 128];   // 16 KB
    const int bn = blockIdx.x;      // 0..255 (N tiles of 128 = 4 j's)
    const int bm = blockIdx.y;      // 0..15  (M tiles of 64)
    const int tid  = threadIdx.x;
    const int wave = tid >> 6;
    const int lane = tid & 63;
    const int wm = wave >> 1;       // 0..1 (rows wm*32)
    const int wn = wave & 1;        // 0..1 (cols wn*64)

    f32x4 acc[2][4] = {};

    // staging: one glds = 8 rows x 128B. lane -> srow = lane>>3, chunk (lane&7)^srow.
    const int srow = lane >> 3;
    const int sch  = (lane & 7) ^ srow;
    const u8* gA0 = A + (size_t)(bm * 64  + wave * 8 + srow) * 512 + sch * 16;
    const u8* gB0 = B + (size_t)(bn * 128 + wave * 8 + srow) * 512 + sch * 16;
    u8* dA = lA + wave * 1024;
    u8* dB = lB + wave * 1024;

    // fragment: lane(frow=l&15, fq=l>>4) holds k-bytes [fq*32, fq*32+32)
    // = chunks {2fq, 2fq+1}, each XOR'd with (row&7).
    const int frow = lane & 15;
    const int fq   = lane >> 4;

    for (int k0 = 0; k0 < 512; k0 += 128) {
#pragma unroll
        for (int j = 0; j < 2; ++j)              // A groups wave+4j (rows +32j)
            gload_lds16(gA0 + k0 + j * 16384, dA + j * 4096);
#pragma unroll
        for (int j = 0; j < 4; ++j)              // B groups wave+4j (rows +32j)
            gload_lds16(gB0 + k0 + j * 16384, dB + j * 4096);
        __syncthreads();

        // hoist the 4 B fragments, stream A one mt at a time
        i32x8 bf[4];
#pragma unroll
        for (int t = 0; t < 4; ++t) {
            const int rb = wn * 64 + t * 16 + frow;
            const int bb = ((rb >> 3) << 10) + ((rb & 7) << 7);
            int4 p0 = *(const int4*)&lB[bb + ((((fq << 1))     ^ (rb & 7)) << 4)];
            int4 p1 = *(const int4*)&lB[bb + ((((fq << 1) | 1) ^ (rb & 7)) << 4)];
            bf[t] = mk8(p0, p1);
        }
#pragma unroll
        for (int mt = 0; mt < 2; ++mt) {
            const int ra = wm * 32 + mt * 16 + frow;
            const int ba = ((ra >> 3) << 10) + ((ra & 7) << 7);
            int4 q0 = *(const int4*)&lA[ba + ((((fq << 1))     ^ (ra & 7)) << 4)];
            int4 q1 = *(const int4*)&lA[ba + ((((fq << 1) | 1) ^ (ra & 7)) << 4)];
            const i32x8 af = mk8(q0, q1);
#pragma unroll
            for (int nt = 0; nt < 4; ++nt)
                acc[mt][nt] = __builtin_amdgcn_mfma_scale_f32_16x16x128_f8f6f4(
                    af, bf[nt], acc[mt][nt],
                    0, 0,          // cbsz=fp8(e4m3), blgp=fp8(e4m3)
                    0, 0x7F,       // scale A = 1.0 (E8M0 127)
                    0, 0x7F);      // scale B = 1.0
        }
        __syncthreads();
    }

    // epilogue: C row = bm*64 + wm*32 + mt*16 + fq*4 + rr ; col = bn*128+wn*64+nt*16+(l&15)
    const float inv = 1.0f / (256.0f * (*temp_ptr));
    const int jb = (bn * 128 + wn * 64) >> 5;
#pragma unroll
    for (int mt = 0; mt < 2; ++mt) {
#pragma unroll
        for (int rr = 0; rr < 4; ++rr) {
            float v0 = fmaxf(acc[mt][0][rr], acc[mt][1][rr]);
            float v1 = fmaxf(acc[mt][2][rr], acc[mt][3][rr]);
#pragma unroll
            for (int off = 1; off < 16; off <<= 1) {
                v0 = fmaxf(v0, __shfl_xor(v0, off));
                v1 = fmaxf(v1, __shfl_xor(v1, off));
            }
            if ((lane & 15) == 0) {
                const int row = bm * 64 + wm * 32 + mt * 16 + fq * 4 + rr;
                sim[row * 1024 + jb]     = v0 * inv;
                sim[row * 1024 + jb + 1] = v1 * inv;
            }
        }
    }
}

// ---------------------------------------------------------------- per-row loss
// ONE WAVE PER ROW, zero LDS, zero barriers. Row (1024 fp32) in 16 regs/lane.
__device__ __forceinline__ u32 f2key(float x) {
    u32 b = __float_as_uint(x);
    return (b & 0x80000000u) ? ~b : (b | 0x80000000u);
}
__device__ __forceinline__ float key2f(u32 k) {
    return __uint_as_float((k & 0x80000000u) ? (k & 0x7fffffffu) : ~k);
}

__global__ __launch_bounds__(256)
void row_loss(const float* __restrict__ sim, float* __restrict__ out) {
    const int tid = threadIdx.x;
    const int lane = tid & 63;
    const int wv = tid >> 6;
    const int i = blockIdx.x * 4 + wv;          // row index

    float v[16];
    const float4* rp = (const float4*)(sim + (size_t)i * 1024);
#pragma unroll
    for (int t = 0; t < 4; ++t) {
        float4 f = rp[t * 64 + lane];
        v[t * 4 + 0] = f.x; v[t * 4 + 1] = f.y; v[t * 4 + 2] = f.z; v[t * 4 + 3] = f.w;
    }

    const int dslot = ((i >> 8) << 2) | (i & 3);
    const int dlane = (i >> 2) & 63;

    u32 k[16];
#pragma unroll
    for (int t = 0; t < 16; ++t) {
        u32 kk = f2key(v[t]);
        k[t] = (lane == dlane && t == dslot) ? 0u : kk;   // diag -> below any finite key
    }

    float pv = 0.f;
#pragma unroll
    for (int t = 0; t < 16; ++t) if (t == dslot) pv = v[t];
    const float pos = __shfl(pv, dlane);

    float m = v[0];
#pragma unroll
    for (int t = 1; t < 16; ++t) m = fmaxf(m, v[t]);
#pragma unroll
    for (int off = 32; off > 0; off >>= 1) m = fmaxf(m, __shfl_xor(m, off));
    float s = 0.f;
#pragma unroll
    for (int t = 0; t < 16; ++t) s += __expf(v[t] - m);
#pragma unroll
    for (int off = 32; off > 0; off >>= 1) s += __shfl_xor(s, off);
    const float loss_std = m + __logf(s) - pos;

    // binary search: largest x with count(key >= x) >= 512
    u32 lo = 0u, hi = 0xFFFFFFFFu;
    while (lo < hi) {
        const u32 span = hi - lo;
        const u32 mid = lo + (span >> 1) + (span & 1u);
        int cnt = 0;
#pragma unroll
        for (int t = 0; t < 16; ++t) cnt += (k[t] >= mid);
#pragma unroll
        for (int off = 32; off > 0; off >>= 1) cnt += __shfl_xor(cnt, off);
        if (cnt >= 512) lo = mid; else hi = mid - 1;
    }
    const u32 t_key = lo;
    const float tval = key2f(t_key);

    float se = 0.f;
    int cgt = 0;
#pragma unroll
    for (int t = 0; t < 16; ++t) {
        if (k[t] > t_key) { se += __expf(v[t] - m); ++cgt; }
    }
#pragma unroll
    for (int off = 32; off > 0; off >>= 1) se += __shfl_xor(se, off);
#pragma unroll
    for (int off = 32; off > 0; off >>= 1) cgt += __shfl_xor(cgt, off);

    const float sh = se + (float)(512 - cgt) * __expf(tval - m) + __expf(pos - m);
    const float hard = m + __logf(sh) - pos;

    if (lane == 0)
        atomicAdd(out, (loss_std + 0.5f * hard) * (1.0f / 1024.0f));
}

// ---------------------------------------------------------------- launch
extern "C" void kernel_launch(void* const* d_in, const int* in_sizes, int n_in,
                              void* d_out, int out_size, void* d_ws, size_t ws_size,
                              hipStream_t stream) {
    const float* F    = (const float*)d_in[0];   // 1024*512
    const float* T    = (const float*)d_in[1];   // 1024*32*512
    const float* temp = (const float*)d_in[2];   // scalar
    float* out = (float*)d_out;

    char* ws = (char*)d_ws;
    u32*  Fb8 = (u32*)ws;                                   // 0.5 MB fp8
    u32*  Tb8 = (u32*)(ws + (1u << 20));                    // 16 MB fp8
    float* sim = (float*)(ws + (1u << 20) + (32u << 20));   // 4 MB

    cvt_fused<<<8448, 256, 0, stream>>>(F, T, Fb8, Tb8, out);

    dim3 grid(256, 16);
    gemm_max<<<grid, 256, 0, stream>>>((const u8*)Fb8, (const u8*)Tb8, temp, sim);

    row_loss<<<256, 256, 0, stream>>>(sim, out);
}

// Round 9
// 159.740 us; speedup vs baseline: 1.3589x; 1.3589x over previous
//
#include <hip/hip_runtime.h>
#include <hip/hip_bf16.h>
#include <math.h>

typedef unsigned short u16;
typedef unsigned char u8;
typedef unsigned int u32;
typedef __attribute__((ext_vector_type(4))) float f32x4;
typedef __attribute__((ext_vector_type(8))) int i32x8;

// -------------------------------------------------- fp32 -> fp8 e4m3 (x16 pre-scale)
// l2-normed inputs: |x| <~ 0.3 -> x*16 in [~0.01, 4.8]: full mantissa, no saturation.
// Dequant folded into the gemm epilogue (divide by 256*temp).
__global__ void cvt_fused(const float* __restrict__ F, const float* __restrict__ T,
                          u32* __restrict__ Fb, u32* __restrict__ Tb,
                          float* __restrict__ out) {
    const int idx = blockIdx.x * blockDim.x + threadIdx.x;
    if (idx == 0) out[0] = 0.f;
    const float* s;
    u32* d;
    int i;
    if (idx < 65536) { s = F; d = Fb; i = idx; }
    else             { s = T; d = Tb; i = idx - 65536; }
    const float4 v0 = *(const float4*)(s + (size_t)i * 8);
    const float4 v1 = *(const float4*)(s + (size_t)i * 8 + 4);
    int lo = __builtin_amdgcn_cvt_pk_fp8_f32(v0.x * 16.f, v0.y * 16.f, 0, false);
    lo     = __builtin_amdgcn_cvt_pk_fp8_f32(v0.z * 16.f, v0.w * 16.f, lo, true);
    int hi = __builtin_amdgcn_cvt_pk_fp8_f32(v1.x * 16.f, v1.y * 16.f, 0, false);
    hi     = __builtin_amdgcn_cvt_pk_fp8_f32(v1.z * 16.f, v1.w * 16.f, hi, true);
    uint2 o; o.x = (u32)lo; o.y = (u32)hi;
    ((uint2*)d)[i] = o;
}

// ---------------------------------------------------------------- GEMM + max
#define GLB_AS __attribute__((address_space(1)))
#define LDS_AS __attribute__((address_space(3)))

__device__ __forceinline__ void gload_lds16(const void* g, void* l) {
    __builtin_amdgcn_global_load_lds((const GLB_AS void*)g, (LDS_AS void*)l, 16, 0, 0);
}

// regs-only operand build: two int4 -> i32x8
__device__ __forceinline__ i32x8 mk8(int4 a, int4 b) {
    i32x8 r;
    r[0] = a.x; r[1] = a.y; r[2] = a.z; r[3] = a.w;
    r[4] = b.x; r[5] = b.y; r[6] = b.z; r[7] = b.w;
    return r;
}

// A: F fp8 [1024 x 512], B: T fp8 [32768 x 512] (row-major, K contiguous, bytes).
// sim[i*1024+j] = max_{q<32} dot(A[i],B[j*32+q]) / (256*temp)
// Tile 128x128, BK=128, __launch_bounds__(256,2) — the ONLY config that avoids
// scratch for this mfma_scale kernel (R6/R8: any higher wave cap spills ~200MB).
//
// Double-buffered LDS (64 KB): stage(k+1) -> other buffer BEFORE compute(k), one
// barrier per K-step — glds overlaps the MFMA phase instead of being drained
// cold by vmcnt(0) at the barrier (R7 was latency-bound: MfmaUtil 14%).
//
// K-permutation: storage chunk s<4 holds logical chunk 2s, s>=4 holds 2s-7
// (same permutation for A and B => dot products unchanged). Frag ds_read_b128
// instr h then reads storage chunks {4h+fq} — CONSECUTIVE across fq, matching
// R4's verified 0-conflict pattern (R5-R8's stride-2 chunks logged 2^21
// SQ_LDS_BANK_CONFLICT). XOR row swizzle s^(row&7) unchanged (R4-proven).
__global__ __launch_bounds__(256, 2)
void gemm_max(const u8* __restrict__ A, const u8* __restrict__ B,
              const float* __restrict__ temp_ptr, float* __restrict__ sim) {
    __shared__ __align__(16) u8 lA0[16384], lB0[16384];
    __shared__ __align__(16) u8 lA1[16384], lB1[16384];
    const int bn = blockIdx.x;      // 0..255 (N tiles of 128 = 4 j's)
    const int bm = blockIdx.y;      // 0..7   (M tiles of 128)
    const int tid  = threadIdx.x;
    const int wave = tid >> 6;
    const int lane = tid & 63;
    const int wm = wave >> 1;
    const int wn = wave & 1;

    f32x4 acc[4][4] = {};

    // staging: one glds = 8 rows x 128B. lane -> srow = lane>>3; storage chunk
    // s = (lane&7)^srow (bank swizzle); fetch GLOBAL chunk g = perm(s).
    const int srow = lane >> 3;
    const int sst  = (lane & 7) ^ srow;
    const int g    = (sst < 4) ? (2 * sst) : (2 * sst - 7);
    const u8* gA0 = A + (size_t)(bm * 128 + wave * 8 + srow) * 512 + g * 16;
    const u8* gB0 = B + (size_t)(bn * 128 + wave * 8 + srow) * 512 + g * 16;
    const int lo_ = wave * 1024;

    const int frow = lane & 15;
    const int fq   = lane >> 4;

#define STAGE(K0, DA, DB)                                                   \
    {                                                                       \
        _Pragma("unroll")                                                   \
        for (int j = 0; j < 4; ++j) {                                       \
            gload_lds16(gA0 + (K0) + j * 16384, (DA) + lo_ + j * 4096);     \
            gload_lds16(gB0 + (K0) + j * 16384, (DB) + lo_ + j * 4096);     \
        }                                                                   \
    }

    // instr h reads storage chunk (4h+fq)^(row&7): h=0 -> logical chunk 2fq
    // (k [fq*32,+16)), h=1 -> logical 2fq+1 (k [fq*32+16,+16)).
#define COMPUTE(LA, LB)                                                     \
    {                                                                       \
        i32x8 bfr[4];                                                       \
        _Pragma("unroll")                                                   \
        for (int t = 0; t < 4; ++t) {                                       \
            const int rb = wn * 64 + t * 16 + frow;                         \
            const int bb = ((rb >> 3) << 10) + ((rb & 7) << 7);             \
            int4 p0 = *(const int4*)&(LB)[bb + (((fq)     ^ (rb & 7)) << 4)]; \
            int4 p1 = *(const int4*)&(LB)[bb + (((4 + fq) ^ (rb & 7)) << 4)]; \
            bfr[t] = mk8(p0, p1);                                           \
        }                                                                   \
        _Pragma("unroll")                                                   \
        for (int mt = 0; mt < 4; ++mt) {                                    \
            const int ra = wm * 64 + mt * 16 + frow;                        \
            const int ba = ((ra >> 3) << 10) + ((ra & 7) << 7);             \
            int4 q0 = *(const int4*)&(LA)[ba + (((fq)     ^ (ra & 7)) << 4)]; \
            int4 q1 = *(const int4*)&(LA)[ba + (((4 + fq) ^ (ra & 7)) << 4)]; \
            const i32x8 afr = mk8(q0, q1);                                  \
            _Pragma("unroll")                                               \
            for (int nt = 0; nt < 4; ++nt)                                  \
                acc[mt][nt] = __builtin_amdgcn_mfma_scale_f32_16x16x128_f8f6f4( \
                    afr, bfr[nt], acc[mt][nt], 0, 0, 0, 0x7F, 0, 0x7F);     \
        }                                                                   \
    }

    STAGE(0, lA0, lB0);
    __syncthreads();
    STAGE(128, lA1, lB1);
    COMPUTE(lA0, lB0);
    __syncthreads();
    STAGE(256, lA0, lB0);
    COMPUTE(lA1, lB1);
    __syncthreads();
    STAGE(384, lA1, lB1);
    COMPUTE(lA0, lB0);
    __syncthreads();
    COMPUTE(lA1, lB1);
#undef STAGE
#undef COMPUTE

    // epilogue: C row = bm*128 + wm*64 + mt*16 + fq*4 + rr ; col = bn*128+wn*64+nt*16+(l&15)
    const float inv = 1.0f / (256.0f * (*temp_ptr));
    const int jb = (bn * 128 + wn * 64) >> 5;
#pragma unroll
    for (int mt = 0; mt < 4; ++mt) {
#pragma unroll
        for (int rr = 0; rr < 4; ++rr) {
            float v0 = fmaxf(acc[mt][0][rr], acc[mt][1][rr]);
            float v1 = fmaxf(acc[mt][2][rr], acc[mt][3][rr]);
#pragma unroll
            for (int off = 1; off < 16; off <<= 1) {
                v0 = fmaxf(v0, __shfl_xor(v0, off));
                v1 = fmaxf(v1, __shfl_xor(v1, off));
            }
            if ((lane & 15) == 0) {
                const int row = bm * 128 + wm * 64 + mt * 16 + fq * 4 + rr;
                __builtin_nontemporal_store(v0 * inv, &sim[row * 1024 + jb]);
                __builtin_nontemporal_store(v1 * inv, &sim[row * 1024 + jb + 1]);
            }
        }
    }
}

// ---------------------------------------------------------------- per-row loss
// ONE WAVE PER ROW, zero LDS, zero barriers. Row (1024 fp32) in 16 regs/lane.
__device__ __forceinline__ u32 f2key(float x) {
    u32 b = __float_as_uint(x);
    return (b & 0x80000000u) ? ~b : (b | 0x80000000u);
}
__device__ __forceinline__ float key2f(u32 k) {
    return __uint_as_float((k & 0x80000000u) ? (k & 0x7fffffffu) : ~k);
}

__global__ __launch_bounds__(256)
void row_loss(const float* __restrict__ sim, float* __restrict__ out) {
    const int tid = threadIdx.x;
    const int lane = tid & 63;
    const int wv = tid >> 6;
    const int i = blockIdx.x * 4 + wv;          // row index

    float v[16];
    const float4* rp = (const float4*)(sim + (size_t)i * 1024);
#pragma unroll
    for (int t = 0; t < 4; ++t) {
        float4 f = rp[t * 64 + lane];
        v[t * 4 + 0] = f.x; v[t * 4 + 1] = f.y; v[t * 4 + 2] = f.z; v[t * 4 + 3] = f.w;
    }

    const int dslot = ((i >> 8) << 2) | (i & 3);
    const int dlane = (i >> 2) & 63;

    u32 k[16];
#pragma unroll
    for (int t = 0; t < 16; ++t) {
        u32 kk = f2key(v[t]);
        k[t] = (lane == dlane && t == dslot) ? 0u : kk;   // diag -> below any finite key
    }

    float pv = 0.f;
#pragma unroll
    for (int t = 0; t < 16; ++t) if (t == dslot) pv = v[t];
    const float pos = __shfl(pv, dlane);

    float m = v[0];
#pragma unroll
    for (int t = 1; t < 16; ++t) m = fmaxf(m, v[t]);
#pragma unroll
    for (int off = 32; off > 0; off >>= 1) m = fmaxf(m, __shfl_xor(m, off));
    float s = 0.f;
#pragma unroll
    for (int t = 0; t < 16; ++t) s += __expf(v[t] - m);
#pragma unroll
    for (int off = 32; off > 0; off >>= 1) s += __shfl_xor(s, off);
    const float loss_std = m + __logf(s) - pos;

    // binary search: largest x with count(key >= x) >= 512
    u32 lo = 0u, hi = 0xFFFFFFFFu;
    while (lo < hi) {
        const u32 span = hi - lo;
        const u32 mid = lo + (span >> 1) + (span & 1u);
        int cnt = 0;
#pragma unroll
        for (int t = 0; t < 16; ++t) cnt += (k[t] >= mid);
#pragma unroll
        for (int off = 32; off > 0; off >>= 1) cnt += __shfl_xor(cnt, off);
        if (cnt >= 512) lo = mid; else hi = mid - 1;
    }
    const u32 t_key = lo;
    const float tval = key2f(t_key);

    float se = 0.f;
    int cgt = 0;
#pragma unroll
    for (int t = 0; t < 16; ++t) {
        if (k[t] > t_key) { se += __expf(v[t] - m); ++cgt; }
    }
#pragma unroll
    for (int off = 32; off > 0; off >>= 1) se += __shfl_xor(se, off);
#pragma unroll
    for (int off = 32; off > 0; off >>= 1) cgt += __shfl_xor(cgt, off);

    const float sh = se + (float)(512 - cgt) * __expf(tval - m) + __expf(pos - m);
    const float hard = m + __logf(sh) - pos;

    if (lane == 0)
        atomicAdd(out, (loss_std + 0.5f * hard) * (1.0f / 1024.0f));
}

// ---------------------------------------------------------------- launch
extern "C" void kernel_launch(void* const* d_in, const int* in_sizes, int n_in,
                              void* d_out, int out_size, void* d_ws, size_t ws_size,
                              hipStream_t stream) {
    const float* F    = (const float*)d_in[0];   // 1024*512
    const float* T    = (const float*)d_in[1];   // 1024*32*512
    const float* temp = (const float*)d_in[2];   // scalar
    float* out = (float*)d_out;

    char* ws = (char*)d_ws;
    u32*  Fb8 = (u32*)ws;                                   // 0.5 MB fp8
    u32*  Tb8 = (u32*)(ws + (1u << 20));                    // 16 MB fp8
    float* sim = (float*)(ws + (1u << 20) + (32u << 20));   // 4 MB

    cvt_fused<<<8448, 256, 0, stream>>>(F, T, Fb8, Tb8, out);

    dim3 grid(256, 8);
    gemm_max<<<grid, 256, 0, stream>>>((const u8*)Fb8, (const u8*)Tb8, temp, sim);

    row_loss<<<256, 256, 0, stream>>>(sim, out);
}

// Round 10
// 158.235 us; speedup vs baseline: 1.3719x; 1.0095x over previous
//
#include <hip/hip_runtime.h>
#include <hip/hip_bf16.h>
#include <math.h>

typedef unsigned short u16;
typedef unsigned char u8;
typedef unsigned int u32;
typedef long long i64;
typedef __attribute__((ext_vector_type(4))) float f32x4;

// -------------------------------------------------- fp32 -> fp8 e4m3 (x16 pre-scale)
// l2-normed inputs: |x| <~ 0.3 -> x*16 in [~0.01, 4.8]: full mantissa, no saturation.
// Dequant folded into gemm epilogue (divide by 256*temp).
//
// K-PERMUTED OUTPUT: within each 128-byte K-block, byte (32s + 8f + b) of the
// logical row is stored at (32f + 8s + b)  [s,f in 0..3, b in 0..7]. Applied to
// BOTH A and B -> dot products unchanged (R9-verified technique). This makes a
// lane's two MFMA sub-step operands contiguous 16B chunks in LDS.
__global__ void cvt_fused(const float* __restrict__ F, const float* __restrict__ T,
                          u32* __restrict__ Fb, u32* __restrict__ Tb,
                          float* __restrict__ out) {
    const int idx = blockIdx.x * blockDim.x + threadIdx.x;
    if (idx == 0) out[0] = 0.f;
    const float* s;
    u32* d;
    int i;
    if (idx < 65536) { s = F; d = Fb; i = idx; }
    else             { s = T; d = Tb; i = idx - 65536; }
    const float4 v0 = *(const float4*)(s + (size_t)i * 8);
    const float4 v1 = *(const float4*)(s + (size_t)i * 8 + 4);
    int lo = __builtin_amdgcn_cvt_pk_fp8_f32(v0.x * 16.f, v0.y * 16.f, 0, false);
    lo     = __builtin_amdgcn_cvt_pk_fp8_f32(v0.z * 16.f, v0.w * 16.f, lo, true);
    int hi = __builtin_amdgcn_cvt_pk_fp8_f32(v1.x * 16.f, v1.y * 16.f, 0, false);
    hi     = __builtin_amdgcn_cvt_pk_fp8_f32(v1.z * 16.f, v1.w * 16.f, hi, true);
    uint2 o; o.x = (u32)lo; o.y = (u32)hi;
    // permuted destination: row r, in-row byte o -> (t<<7)|(f<<5)|(s<<3)
    const int r  = i >> 6;                 // 64 8-byte groups per 512-elem row
    const int ob = (i & 63) << 3;          // in-row byte offset (multiple of 8)
    const int t  = ob >> 7;
    const int ss = (ob >> 5) & 3;
    const int f  = (ob >> 3) & 3;
    const int o2 = (t << 7) | (f << 5) | (ss << 3);
    ((uint2*)d)[r * 64 + (o2 >> 3)] = o;
}

// ---------------------------------------------------------------- GEMM + max
#define GLB_AS __attribute__((address_space(1)))
#define LDS_AS __attribute__((address_space(3)))

__device__ __forceinline__ void gload_lds16(const void* g, void* l) {
    __builtin_amdgcn_global_load_lds((const GLB_AS void*)g, (LDS_AS void*)l, 16, 0, 0);
}

__device__ __forceinline__ i64 half0(int4 v) { int2 p; p.x = v.x; p.y = v.y; return __builtin_bit_cast(i64, p); }
__device__ __forceinline__ i64 half1(int4 v) { int2 p; p.x = v.z; p.y = v.w; return __builtin_bit_cast(i64, p); }

// A: F fp8 [1024 x 512], B: T fp8 [32768 x 512] (row-major, K-permuted per cvt).
// sim[i*1024+j] = max_{q<32} dot(A[i],B[j*32+q]) / (256*temp)
//
// R10 redesign: NON-SCALED mfma_f32_16x16x32_fp8_fp8 (2-VGPR operands).
// Rationale: R7/R9 were latency-bound (MfmaUtil 14%, pipe floors ~3x below dur)
// and every attempt to raise occupancy with mfma_scale's 8-reg i32x8 operands
// spilled catastrophically (R6/R8: 200-500 MB scratch). Light operands ->
// BM=64 x BN=128 x BK=128, wave-tile 32x64: acc 32 + frags 24 + addr ~25 regs
// << 128 cap of __launch_bounds__(256,4); LDS 24 KB single-buffer -> 4 blocks/CU
// (16 waves/CU, 2x R9). MFMA floor rises 7.4 -> 14.5 us (bf16 rate) but latency
// dominates both.
//
// LDS: row-major 128-B rows; 16B chunk c of row r stored at slot c^(r&7)
// (R4/R9-verified conflict-free). With the cvt K-permutation, lane (frow,fq)
// reads chunks {2fq, 2fq+1}: b128 #0 = sub-steps s0,s1 (dwords 01|23), #1 = s2,s3.
__global__ __launch_bounds__(256, 4)
void gemm_max(const u8* __restrict__ A, const u8* __restrict__ B,
              const float* __restrict__ temp_ptr, float* __restrict__ sim) {
    __shared__ __align__(16) u8 lA[64 * 128];    //  8 KB
    __shared__ __align__(16) u8 lB[128 * 128];   // 16 KB
    const int bn = blockIdx.x;      // 0..255 (N tiles of 128 B-rows = 4 j's)
    const int bm = blockIdx.y;      // 0..15  (M tiles of 64)
    const int tid  = threadIdx.x;
    const int wave = tid >> 6;
    const int lane = tid & 63;
    const int wm = wave >> 1;       // 0..1: rows wm*32
    const int wn = wave & 1;        // 0..1: cols wn*64

    f32x4 acc[2][4] = {};

    // staging: one glds = 8 rows x 128B. lane -> srow = lane>>3, slot chunk l&7
    // holds global chunk (l&7)^srow.
    const int srow = lane >> 3;
    const int aoff = srow * 512 + (((lane & 7) ^ srow) << 4);   // per-lane global offset
    const u8* gA = A + (size_t)(bm * 64)  * 512 + aoff;         // + ga*4096 + k0
    const u8* gB = B + (size_t)(bn * 128) * 512 + aoff;         // + gb*4096 + k0

    const int frow = lane & 15;
    const int fq   = lane >> 4;
    const int r7   = frow & 7;

    for (int k0 = 0; k0 < 512; k0 += 128) {
        // A: groups {wave, wave+4} of 8 rows; B: groups {wave+4j}
        gload_lds16(gA + (wave)     * 4096 + k0, lA + (wave)     * 1024);
        gload_lds16(gA + (wave + 4) * 4096 + k0, lA + (wave + 4) * 1024);
#pragma unroll
        for (int j = 0; j < 4; ++j)
            gload_lds16(gB + (wave + 4 * j) * 4096 + k0, lB + (wave + 4 * j) * 1024);
        __syncthreads();

#pragma unroll
        for (int sp = 0; sp < 2; ++sp) {
            const int coff = (((fq << 1) + sp) ^ r7) << 4;
            int4 aF[2], bF[4];
#pragma unroll
            for (int mt = 0; mt < 2; ++mt)
                aF[mt] = *(const int4*)&lA[(wm * 32 + mt * 16 + frow) * 128 + coff];
#pragma unroll
            for (int nt = 0; nt < 4; ++nt)
                bF[nt] = *(const int4*)&lB[(wn * 64 + nt * 16 + frow) * 128 + coff];
#pragma unroll
            for (int mt = 0; mt < 2; ++mt)
#pragma unroll
                for (int nt = 0; nt < 4; ++nt) {
                    acc[mt][nt] = __builtin_amdgcn_mfma_f32_16x16x32_fp8_fp8(
                        half0(aF[mt]), half0(bF[nt]), acc[mt][nt], 0, 0, 0);
                    acc[mt][nt] = __builtin_amdgcn_mfma_f32_16x16x32_fp8_fp8(
                        half1(aF[mt]), half1(bF[nt]), acc[mt][nt], 0, 0, 0);
                }
        }
        __syncthreads();
    }

    // epilogue: C row = bm*64 + wm*32 + mt*16 + fq*4 + rr ; col = bn*128+wn*64+nt*16+(l&15)
    const float inv = 1.0f / (256.0f * (*temp_ptr));
    const int jb = (bn * 128 + wn * 64) >> 5;
#pragma unroll
    for (int mt = 0; mt < 2; ++mt) {
#pragma unroll
        for (int rr = 0; rr < 4; ++rr) {
            float v0 = fmaxf(acc[mt][0][rr], acc[mt][1][rr]);
            float v1 = fmaxf(acc[mt][2][rr], acc[mt][3][rr]);
#pragma unroll
            for (int off = 1; off < 16; off <<= 1) {
                v0 = fmaxf(v0, __shfl_xor(v0, off));
                v1 = fmaxf(v1, __shfl_xor(v1, off));
            }
            if ((lane & 15) == 0) {
                const int row = bm * 64 + wm * 32 + mt * 16 + fq * 4 + rr;
                sim[row * 1024 + jb]     = v0 * inv;
                sim[row * 1024 + jb + 1] = v1 * inv;
            }
        }
    }
}

// ---------------------------------------------------------------- per-row loss
// ONE WAVE PER ROW, zero LDS, zero barriers. Row (1024 fp32) in 16 regs/lane.
__device__ __forceinline__ u32 f2key(float x) {
    u32 b = __float_as_uint(x);
    return (b & 0x80000000u) ? ~b : (b | 0x80000000u);
}
__device__ __forceinline__ float key2f(u32 k) {
    return __uint_as_float((k & 0x80000000u) ? (k & 0x7fffffffu) : ~k);
}

__global__ __launch_bounds__(256)
void row_loss(const float* __restrict__ sim, float* __restrict__ out) {
    const int tid = threadIdx.x;
    const int lane = tid & 63;
    const int wv = tid >> 6;
    const int i = blockIdx.x * 4 + wv;          // row index

    float v[16];
    const float4* rp = (const float4*)(sim + (size_t)i * 1024);
#pragma unroll
    for (int t = 0; t < 4; ++t) {
        float4 f = rp[t * 64 + lane];
        v[t * 4 + 0] = f.x; v[t * 4 + 1] = f.y; v[t * 4 + 2] = f.z; v[t * 4 + 3] = f.w;
    }

    const int dslot = ((i >> 8) << 2) | (i & 3);
    const int dlane = (i >> 2) & 63;

    u32 k[16];
#pragma unroll
    for (int t = 0; t < 16; ++t) {
        u32 kk = f2key(v[t]);
        k[t] = (lane == dlane && t == dslot) ? 0u : kk;   // diag -> below any finite key
    }

    float pv = 0.f;
#pragma unroll
    for (int t = 0; t < 16; ++t) if (t == dslot) pv = v[t];
    const float pos = __shfl(pv, dlane);

    float m = v[0];
#pragma unroll
    for (int t = 1; t < 16; ++t) m = fmaxf(m, v[t]);
#pragma unroll
    for (int off = 32; off > 0; off >>= 1) m = fmaxf(m, __shfl_xor(m, off));
    float s = 0.f;
#pragma unroll
    for (int t = 0; t < 16; ++t) s += __expf(v[t] - m);
#pragma unroll
    for (int off = 32; off > 0; off >>= 1) s += __shfl_xor(s, off);
    const float loss_std = m + __logf(s) - pos;

    // binary search: largest x with count(key >= x) >= 512
    u32 lo = 0u, hi = 0xFFFFFFFFu;
    while (lo < hi) {
        const u32 span = hi - lo;
        const u32 mid = lo + (span >> 1) + (span & 1u);
        int cnt = 0;
#pragma unroll
        for (int t = 0; t < 16; ++t) cnt += (k[t] >= mid);
#pragma unroll
        for (int off = 32; off > 0; off >>= 1) cnt += __shfl_xor(cnt, off);
        if (cnt >= 512) lo = mid; else hi = mid - 1;
    }
    const u32 t_key = lo;
    const float tval = key2f(t_key);

    float se = 0.f;
    int cgt = 0;
#pragma unroll
    for (int t = 0; t < 16; ++t) {
        if (k[t] > t_key) { se += __expf(v[t] - m); ++cgt; }
    }
#pragma unroll
    for (int off = 32; off > 0; off >>= 1) se += __shfl_xor(se, off);
#pragma unroll
    for (int off = 32; off > 0; off >>= 1) cgt += __shfl_xor(cgt, off);

    const float sh = se + (float)(512 - cgt) * __expf(tval - m) + __expf(pos - m);
    const float hard = m + __logf(sh) - pos;

    if (lane == 0)
        atomicAdd(out, (loss_std + 0.5f * hard) * (1.0f / 1024.0f));
}

// ---------------------------------------------------------------- launch
extern "C" void kernel_launch(void* const* d_in, const int* in_sizes, int n_in,
                              void* d_out, int out_size, void* d_ws, size_t ws_size,
                              hipStream_t stream) {
    const float* F    = (const float*)d_in[0];   // 1024*512
    const float* T    = (const float*)d_in[1];   // 1024*32*512
    const float* temp = (const float*)d_in[2];   // scalar
    float* out = (float*)d_out;

    char* ws = (char*)d_ws;
    u32*  Fb8 = (u32*)ws;                                   // 0.5 MB fp8
    u32*  Tb8 = (u32*)(ws + (1u << 20));                    // 16 MB fp8
    float* sim = (float*)(ws + (1u << 20) + (32u << 20));   // 4 MB

    cvt_fused<<<8448, 256, 0, stream>>>(F, T, Fb8, Tb8, out);

    dim3 grid(256, 16);
    gemm_max<<<grid, 256, 0, stream>>>((const u8*)Fb8, (const u8*)Tb8, temp, sim);

    row_loss<<<256, 256, 0, stream>>>(sim, out);
}